// Round 1
// baseline (4421.238 us; speedup 1.0000x reference)
//
#include <hip/hip_runtime.h>

// ---------------------------------------------------------------------------
// VanillaRNN on MI355X.
//   B=64, T=512, I=512, H=1024, C=1000.
// Phase 1+2 fused into ONE persistent kernel (64 WGs):
//   - 4 batch-groups (16 rows) x 16 column-slices (64 cols).
//   - Wh and Wx held in VGPRs as pre-converted bf16 MFMA B-fragments.
//   - per-step producer/consumer sync via per-wave flags (agent-scope
//     release/acquire). ws poison 0xAAAAAAAA < 0 == "not ready" -> no init.
//   - h history written to ws (512 x 64 x 1024 bf16 = 64 MB).
// Phase 3: small fp32 GEMV-style kernel for logits.
// ---------------------------------------------------------------------------

typedef __bf16 bf16x8 __attribute__((ext_vector_type(8)));
typedef float  f32x4  __attribute__((ext_vector_type(4)));

#define B_SZ 64
#define T_SZ 512
#define IDIM 512
#define HDIM 1024
#define NCLS 1000

#define XP 520    // x LDS row stride (shorts): 512 + 8 pad (16B-aligned rows)
#define HP 1032   // h LDS row stride: 1024 + 8 pad

__device__ __forceinline__ float tanh_fast(float v) {
    // tanh(v) = 1 - 2/(exp(2v)+1);  exp(2v) = exp2(v * 2*log2(e))
    float e = __builtin_amdgcn_exp2f(v * 2.885390081777927f);
    return 1.f - 2.f * __builtin_amdgcn_rcpf(e + 1.f);
}

// MFMA 16x16x32 bf16 fragment layouts (guide §3, m89/m91/m120 verified):
//   A[m = lane&15][k = (lane>>4)*8 + j]   j=0..7
//   B[k = (lane>>4)*8 + j][n = lane&15]
//   D[row = (lane>>4)*4 + r][col = lane&15]

__global__ __launch_bounds__(256, 1)
void rnn_persistent(const float* __restrict__ x,    // (64,512,512)
                    const float* __restrict__ Wx,   // (1024,512)
                    const float* __restrict__ bx,   // (1024)
                    const float* __restrict__ Wh,   // (1024,1024)
                    __bf16* __restrict__ h_hist,    // (512,64,1024) bf16, ws
                    int* __restrict__ flags)        // (4*64) per-wave flags, ws
{
    __shared__ __bf16 xlds[16 * XP];
    __shared__ __bf16 hlds[16 * HP];

    const int g    = blockIdx.x >> 4;   // batch group 0..3  (rows g*16..+15)
    const int c    = blockIdx.x & 15;   // column slice 0..15 (cols c*64..+63)
    const int wv   = threadIdx.x >> 6;  // wave 0..3 (owns 16 cols)
    const int lane = threadIdx.x & 63;
    const int l15  = lane & 15;
    const int quad = lane >> 4;
    const int nabs = c * 64 + wv * 16 + l15;   // this lane's output column

    // ---- one-time init: Wx (16 ksteps) + Wh (32 ksteps) B-fragments in VGPRs
    bf16x8 wxf[16];
    bf16x8 whf[32];
#pragma unroll
    for (int kk = 0; kk < 16; ++kk) {
        const float4* p = (const float4*)(Wx + (size_t)nabs * IDIM + kk * 32 + quad * 8);
        float4 a = p[0], b = p[1];
        bf16x8 v;
        v[0]=(__bf16)a.x; v[1]=(__bf16)a.y; v[2]=(__bf16)a.z; v[3]=(__bf16)a.w;
        v[4]=(__bf16)b.x; v[5]=(__bf16)b.y; v[6]=(__bf16)b.z; v[7]=(__bf16)b.w;
        wxf[kk] = v;
    }
#pragma unroll
    for (int kk = 0; kk < 32; ++kk) {
        const float4* p = (const float4*)(Wh + (size_t)nabs * HDIM + kk * 32 + quad * 8);
        float4 a = p[0], b = p[1];
        bf16x8 v;
        v[0]=(__bf16)a.x; v[1]=(__bf16)a.y; v[2]=(__bf16)a.z; v[3]=(__bf16)a.w;
        v[4]=(__bf16)b.x; v[5]=(__bf16)b.y; v[6]=(__bf16)b.z; v[7]=(__bf16)b.w;
        whf[kk] = v;
    }
    const float bxv = bx[nabs];

    // staging thread mapping
    const int sr = threadIdx.x >> 4;        // row 0..15 within batch group
    const int sc = threadIdx.x & 15;        // chunk 0..15

    for (int t = 1; t <= T_SZ; ++t) {
        // ---- A: stage x[g*16+sr][t-1][sc*32 .. +32) -> bf16 LDS ------------
        {
            const float4* p4 = (const float4*)(x + ((size_t)(g * 16 + sr) * T_SZ + (t - 1)) * IDIM + sc * 32);
            float4 f[8];
#pragma unroll
            for (int i = 0; i < 8; ++i) f[i] = p4[i];
            __bf16* dst = xlds + sr * XP + sc * 32;
#pragma unroll
            for (int i = 0; i < 4; ++i) {
                float4 a = f[2 * i], b = f[2 * i + 1];
                bf16x8 v;
                v[0]=(__bf16)a.x; v[1]=(__bf16)a.y; v[2]=(__bf16)a.z; v[3]=(__bf16)a.w;
                v[4]=(__bf16)b.x; v[5]=(__bf16)b.y; v[6]=(__bf16)b.z; v[7]=(__bf16)b.w;
                *(bf16x8*)(dst + i * 8) = v;
            }
        }
        __syncthreads();   // sync1: xlds ready (also WAR-guards hlds of prev step)

        // ---- B: xh accumulation (K=512, no dependency on h) ----------------
        f32x4 acc0 = {0.f, 0.f, 0.f, 0.f};
        f32x4 acc1 = {0.f, 0.f, 0.f, 0.f};
#pragma unroll
        for (int kk = 0; kk < 16; kk += 2) {
            bf16x8 a0 = *(const bf16x8*)(xlds + l15 * XP + kk * 32 + quad * 8);
            acc0 = __builtin_amdgcn_mfma_f32_16x16x32_bf16(a0, wxf[kk], acc0, 0, 0, 0);
            bf16x8 a1 = *(const bf16x8*)(xlds + l15 * XP + (kk + 1) * 32 + quad * 8);
            acc1 = __builtin_amdgcn_mfma_f32_16x16x32_bf16(a1, wxf[kk + 1], acc1, 0, 0, 0);
        }

        // ---- C: wait for h_{t-1} chunks from the 64 waves of my group ------
        if (t > 1) {
            int* fl = flags + g * 64;
            int ready;
            do {
                int f = __hip_atomic_load(fl + lane, __ATOMIC_RELAXED, __HIP_MEMORY_SCOPE_AGENT);
                ready = __all(f >= t - 1);
                if (!ready) __builtin_amdgcn_s_sleep(1);
            } while (!ready);
            __builtin_amdgcn_fence(__ATOMIC_ACQUIRE, "agent");
            // stage h_{t-1} (slot t-2): 16 x 1024 bf16 -> padded LDS
            const bf16x8* hp = (const bf16x8*)(h_hist + ((size_t)(t - 2) * B_SZ + g * 16 + sr) * HDIM + sc * 64);
            __bf16* hd = hlds + sr * HP + sc * 64;
#pragma unroll
            for (int i = 0; i < 8; ++i) *(bf16x8*)(hd + i * 8) = hp[i];
        }
        __syncthreads();   // sync2: hlds ready

        // ---- D: h_{t-1} @ Wh^T accumulation (K=1024) -----------------------
        if (t > 1) {
#pragma unroll
            for (int kk = 0; kk < 32; kk += 2) {
                bf16x8 a0 = *(const bf16x8*)(hlds + l15 * HP + kk * 32 + quad * 8);
                acc0 = __builtin_amdgcn_mfma_f32_16x16x32_bf16(a0, whf[kk], acc0, 0, 0, 0);
                bf16x8 a1 = *(const bf16x8*)(hlds + l15 * HP + (kk + 1) * 32 + quad * 8);
                acc1 = __builtin_amdgcn_mfma_f32_16x16x32_bf16(a1, whf[kk + 1], acc1, 0, 0, 0);
            }
        }

        // ---- E: tanh epilogue, write h_t chunk (slot t-1) ------------------
        {
            __bf16* hout = h_hist + (size_t)(t - 1) * B_SZ * HDIM;
#pragma unroll
            for (int r = 0; r < 4; ++r) {
                float a  = acc0[r] + acc1[r] + bxv;
                float th = tanh_fast(a);
                int   m  = quad * 4 + r;   // D-layout row = batch-in-group
                hout[(size_t)(g * 16 + m) * HDIM + nabs] = (__bf16)th;
            }
        }

        // ---- F: publish (per-wave flag, agent-scope release) ---------------
        __builtin_amdgcn_fence(__ATOMIC_RELEASE, "agent");
        if (lane == 0)
            __hip_atomic_store(flags + g * 64 + c * 4 + wv, t, __ATOMIC_RELAXED, __HIP_MEMORY_SCOPE_AGENT);
    }
}

// ---------------------------------------------------------------------------
// logits[b][j] = sum_k hT[b][k] * Wy[j][k] + by[j]   (fp32 compute)
// grid = 1000 (one class per WG); thread (q,b): q = k-quarter, b = batch.
// ---------------------------------------------------------------------------
__global__ __launch_bounds__(256)
void logits_k(const __bf16* __restrict__ hT,   // (64,1024) bf16
              const float* __restrict__ Wy,    // (1000,1024)
              const float* __restrict__ by,    // (1000)
              float* __restrict__ out)         // (64,1000)
{
    const int j = blockIdx.x;
    const int q = threadIdx.x & 3;
    const int b = threadIdx.x >> 2;
    const float*  wr = Wy + (size_t)j * HDIM + q * 256;
    const __bf16* hr = hT + (size_t)b * HDIM + q * 256;
    float s = 0.f;
#pragma unroll 8
    for (int kk = 0; kk < 32; ++kk) {
        bf16x8 h8 = *(const bf16x8*)(hr + kk * 8);
        float4 w0 = *(const float4*)(wr + kk * 8);
        float4 w1 = *(const float4*)(wr + kk * 8 + 4);
        s += w0.x * (float)h8[0] + w0.y * (float)h8[1] + w0.z * (float)h8[2] + w0.w * (float)h8[3]
           + w1.x * (float)h8[4] + w1.y * (float)h8[5] + w1.z * (float)h8[6] + w1.w * (float)h8[7];
    }
    s += __shfl_xor(s, 1);
    s += __shfl_xor(s, 2);
    if (q == 0) out[b * NCLS + j] = s + by[j];
}

extern "C" void kernel_launch(void* const* d_in, const int* in_sizes, int n_in,
                              void* d_out, int out_size, void* d_ws, size_t ws_size,
                              hipStream_t stream) {
    (void)in_sizes; (void)n_in; (void)out_size; (void)ws_size;
    const float* x  = (const float*)d_in[0];
    const float* Wx = (const float*)d_in[1];
    const float* bx = (const float*)d_in[2];
    const float* Wh = (const float*)d_in[3];
    const float* Wy = (const float*)d_in[4];
    const float* by = (const float*)d_in[5];

    __bf16* h_hist = (__bf16*)d_ws;                                   // 64 MB
    int*    flags  = (int*)((char*)d_ws + (size_t)T_SZ * B_SZ * HDIM * 2);

    rnn_persistent<<<dim3(64), dim3(256), 0, stream>>>(x, Wx, bx, Wh, h_hist, flags);

    const __bf16* hT = h_hist + (size_t)(T_SZ - 1) * B_SZ * HDIM;
    logits_k<<<dim3(NCLS), dim3(256), 0, stream>>>(hT, Wy, by, (float*)d_out);
}